// Round 2
// baseline (1060.820 us; speedup 1.0000x reference)
//
#include <hip/hip_runtime.h>

// CausalWindowedAttention: B=2,H=16,S=2048,D=64, window=256, temp=8
// Outputs: out [B,H,S,D] fp32, attn [B,H,S,S] fp32 (concatenated in d_out).
// Store-BW-bound (536 MB attn write). One block = 16 query rows.
// R2: regular stores (nt caused partial-line RMW => 1.5x WRITE inflation),
//     LDS 50.4KB => 3 blocks/CU, zero-region stores issued before barriers.

#define S_LEN 2048
#define DHEAD 64
#define TQ 16
#define UEXT 272      // staged key-column extent per block: j in [i0-256, i0+16)
#define SC_STRIDE 276 // halfs; 552 B rows
#define KV_STRIDE 72  // halfs; 144 B rows (16B-aligned for ds_read_b128)

typedef float     f4v __attribute__((ext_vector_type(4)));
typedef _Float16  h2v __attribute__((ext_vector_type(2)));
typedef _Float16  h4v __attribute__((ext_vector_type(4)));

__device__ __forceinline__ float dot2f(float aBits, float bBits, float c) {
#if __has_builtin(__builtin_amdgcn_fdot2)
  return __builtin_amdgcn_fdot2(__builtin_bit_cast(h2v, aBits),
                                __builtin_bit_cast(h2v, bBits), c, false);
#else
  h2v a = __builtin_bit_cast(h2v, aBits);
  h2v b = __builtin_bit_cast(h2v, bBits);
  return c + (float)a.x * (float)b.x + (float)a.y * (float)b.y;
#endif
}

__global__ __launch_bounds__(256, 3)
void cwa_kernel(const float* __restrict__ q, const float* __restrict__ k,
                const float* __restrict__ v, float* __restrict__ out,
                float* __restrict__ attn)
{
  __shared__ __align__(16) _Float16 kv[UEXT][KV_STRIDE];  // K window, then V window
  __shared__ __align__(16) _Float16 kq[TQ][DHEAD];        // Q tile (f16)
  __shared__ __align__(16) _Float16 sc[TQ][SC_STRIDE];    // unnormalized exp scores
  __shared__ float rsum[4][TQ];
  __shared__ float rinv[TQ];

  const int t    = threadIdx.x;
  const int lane = t & 63;
  const int wv   = t >> 6;       // wave 0..3
  const int trow = lane >> 4;    // 0..3
  const int tcol = lane & 15;    // 0..15

  const int blk   = blockIdx.x;
  const int bh    = blk >> 7;          // / 128 tiles
  const int i0    = (blk & 127) * TQ;  // first query row of tile
  const int jbase = i0 - 256;          // global key row of staged column u=0

  const size_t base = (size_t)bh * (S_LEN * DHEAD);
  const float* qb = q + base;
  const float* kb = k + base;
  const float* vb = v + base;
  float* abase = attn + (size_t)(bh * S_LEN + i0) * S_LEN;

  const f4v fzero = {0.f, 0.f, 0.f, 0.f};

  // ---------------- P0: stage Q tile + K window as f16 ----------------
  {
    const int r = t >> 4, d4 = t & 15;
    f4v f = *(const f4v*)(qb + (size_t)(i0 + r) * DHEAD + 4 * d4);
    h4v h = { (_Float16)f.x, (_Float16)f.y, (_Float16)f.z, (_Float16)f.w };
    *(h4v*)&kq[r][4 * d4] = h;
  }
  #pragma unroll 4
  for (int w = 0; w < 17; ++w) {
    const int idx = t + 256 * w;       // 0..4351
    const int u = idx >> 4, d4 = idx & 15;
    const int j = jbase + u;
    f4v f = fzero;                      // zero-fill OOB rows
    if (j >= 0 && j < S_LEN) f = *(const f4v*)(kb + (size_t)j * DHEAD + 4 * d4);
    h4v h = { (_Float16)f.x, (_Float16)f.y, (_Float16)f.z, (_Float16)f.w };
    *(h4v*)&kv[u][4 * d4] = h;
  }

  // ---------------- Z: zero-region attn writes (no data dependency) ----------
  // Issued before the first barrier so the 469MB stream drains under compute.
  {
    const int jb0    = jbase > 0 ? jbase : 0;       // multiple of 16
    const int npre4  = jb0 >> 2;                    // float4s before window
    const int npost4 = (S_LEN - (i0 + TQ)) >> 2;    // float4s after window
    for (int r = 0; r < TQ; ++r) {
      float* rowp = abase + (size_t)r * S_LEN;
      for (int c = t; c < npre4; c += 256)
        *(f4v*)(rowp + 4 * c) = fzero;
      float* rowq = rowp + (i0 + TQ);
      for (int c = t; c < npost4; c += 256)
        *(f4v*)(rowq + 4 * c) = fzero;
    }
  }
  __syncthreads();

  // ---------------- P1: QK^T (f16 dot2), mask, exp, row sums ----------------
  {
    float acc[4][5];
    #pragma unroll
    for (int i = 0; i < 4; ++i)
      #pragma unroll
      for (int j = 0; j < 5; ++j) acc[i][j] = 0.f;

    const int cbase = 68 * wv + tcol;  // wave owns columns [68*wv, 68*wv+68)

    for (int ds2 = 0; ds2 < 8; ++ds2) {
      f4v qr[4], kr[5];
      #pragma unroll
      for (int i = 0; i < 4; ++i)
        qr[i] = *(const f4v*)&kq[trow + 4 * i][8 * ds2];
      #pragma unroll
      for (int j = 0; j < 4; ++j)
        kr[j] = *(const f4v*)&kv[cbase + 16 * j][8 * ds2];
      kr[4] = (tcol < 4) ? *(const f4v*)&kv[cbase + 64][8 * ds2] : fzero;

      #pragma unroll
      for (int i = 0; i < 4; ++i) {
        #pragma unroll
        for (int j = 0; j < 5; ++j) {
          float a = acc[i][j];
          a = dot2f(qr[i].x, kr[j].x, a);
          a = dot2f(qr[i].y, kr[j].y, a);
          a = dot2f(qr[i].z, kr[j].z, a);
          a = dot2f(qr[i].w, kr[j].w, a);
          acc[i][j] = a;
        }
      }
    }

    float rs[4] = {0.f, 0.f, 0.f, 0.f};
    #pragma unroll
    for (int i = 0; i < 4; ++i) {
      const int r = trow + 4 * i;
      #pragma unroll
      for (int j = 0; j < 5; ++j) {
        if (j == 4 && tcol >= 4) continue;   // only tcol<4 own a 5th column
        const int u = cbase + 16 * j;
        // window: u in [r+1, r+256]; j_global >= 0 <=> u >= 256 - i0
        const bool valid = (u >= r + 1) && (u <= r + 256) && (u >= 256 - i0);
        const float p = valid ? __expf(acc[i][j] * 0.125f) : 0.f;
        sc[r][u] = (_Float16)p;
        rs[i] += p;
      }
    }
    #pragma unroll
    for (int off = 8; off > 0; off >>= 1) {
      #pragma unroll
      for (int i = 0; i < 4; ++i) rs[i] += __shfl_down(rs[i], off, 64);
    }
    if (tcol == 0) {
      #pragma unroll
      for (int i = 0; i < 4; ++i) rsum[wv][trow + 4 * i] = rs[i];
    }
  }
  __syncthreads();

  // ---------------- P2: stage V (overwrites kv) + 1/rowsum ----------------
  #pragma unroll 4
  for (int w = 0; w < 17; ++w) {
    const int idx = t + 256 * w;
    const int u = idx >> 4, d4 = idx & 15;
    const int j = jbase + u;
    f4v f = fzero;
    if (j >= 0 && j < S_LEN) f = *(const f4v*)(vb + (size_t)j * DHEAD + 4 * d4);
    h4v h = { (_Float16)f.x, (_Float16)f.y, (_Float16)f.z, (_Float16)f.w };
    *(h4v*)&kv[u][4 * d4] = h;
  }
  if (t < TQ) {
    rinv[t] = 1.f / (rsum[0][t] + rsum[1][t] + rsum[2][t] + rsum[3][t]);
  }
  __syncthreads();

  // ---------------- P3: PV (d-split across waves; no partials) + out store ---
  {
    const int prow = lane >> 2;          // 0..15 (query row)
    const int dq   = lane & 3;           // 0..3
    const int d0   = 16 * wv + 4 * dq;   // this lane's 4 d-columns
    f4v acc = fzero;

    for (int u4 = 0; u4 < 68; ++u4) {
      const int u = 4 * u4;
      h4v ph = *(const h4v*)&sc[prow][u];
      h4v v0 = *(const h4v*)&kv[u + 0][d0];
      h4v v1 = *(const h4v*)&kv[u + 1][d0];
      h4v v2 = *(const h4v*)&kv[u + 2][d0];
      h4v v3 = *(const h4v*)&kv[u + 3][d0];
      const float p0 = (float)ph.x, p1 = (float)ph.y;
      const float p2 = (float)ph.z, p3 = (float)ph.w;
      acc.x = fmaf(p0, (float)v0.x, acc.x); acc.y = fmaf(p0, (float)v0.y, acc.y);
      acc.z = fmaf(p0, (float)v0.z, acc.z); acc.w = fmaf(p0, (float)v0.w, acc.w);
      acc.x = fmaf(p1, (float)v1.x, acc.x); acc.y = fmaf(p1, (float)v1.y, acc.y);
      acc.z = fmaf(p1, (float)v1.z, acc.z); acc.w = fmaf(p1, (float)v1.w, acc.w);
      acc.x = fmaf(p2, (float)v2.x, acc.x); acc.y = fmaf(p2, (float)v2.y, acc.y);
      acc.z = fmaf(p2, (float)v2.z, acc.z); acc.w = fmaf(p2, (float)v2.w, acc.w);
      acc.x = fmaf(p3, (float)v3.x, acc.x); acc.y = fmaf(p3, (float)v3.y, acc.y);
      acc.z = fmaf(p3, (float)v3.z, acc.z); acc.w = fmaf(p3, (float)v3.w, acc.w);
    }
    const float inv = rinv[prow];
    f4v o = { acc.x * inv, acc.y * inv, acc.z * inv, acc.w * inv };
    *(f4v*)(out + (size_t)(bh * S_LEN + i0 + prow) * DHEAD + d0) = o;
  }

  // ---------------- P4: band attn writes (sc * rinv) ----------------
  for (int idx = t; idx < TQ * 68; idx += 256) {
    const int r  = idx / 68;
    const int u4 = idx - 68 * r;
    const int j  = jbase + 4 * u4;
    if (j < 0) continue;                 // j<0 columns don't exist
    h4v ph = *(const h4v*)&sc[r][4 * u4];
    const float inv = rinv[r];
    f4v val = { (float)ph.x * inv, (float)ph.y * inv,
                (float)ph.z * inv, (float)ph.w * inv };
    *(f4v*)(abase + (size_t)r * S_LEN + j) = val;
  }
}

extern "C" void kernel_launch(void* const* d_in, const int* in_sizes, int n_in,
                              void* d_out, int out_size, void* d_ws, size_t ws_size,
                              hipStream_t stream) {
  const float* q = (const float*)d_in[0];
  const float* k = (const float*)d_in[1];
  const float* v = (const float*)d_in[2];
  float* out  = (float*)d_out;
  float* attn = out + (size_t)2 * 16 * 2048 * 64;   // out first, then attn

  dim3 grid(4096), block(256);                      // 32 bh * 128 tiles
  hipLaunchKernelGGL(cwa_kernel, grid, block, 0, stream, q, k, v, out, attn);
}

// Round 3
// 1044.862 us; speedup vs baseline: 1.0153x; 1.0153x over previous
//
#include <hip/hip_runtime.h>

// CausalWindowedAttention: B=2,H=16,S=2048,D=64, window=256, temp=8
// Outputs: out [B,H,S,D] fp32, attn [B,H,S,S] fp32 (concatenated in d_out).
// R3: hipMemsetAsync zeros the attn tensor (full-line writes, no RMW /
//     write-allocate pathology); kernel writes only the 67MB band + out.
//     PV uses transposed V (vt[d][u]) + v_dot2_f32_f16 => no per-lane f16->f32
//     conversions (was 60% of VALU). Band stores issue before PV compute.

#define S_LEN 2048
#define DHEAD 64
#define TQ 16
#define UEXT 272      // staged key-column extent per block: j in [i0-256, i0+16)
#define SC_STRIDE 276 // halfs; 552 B rows
#define KV_STRIDE 72  // halfs; K layout [u][72]
#define VT_STRIDE 276 // halfs; V^T layout [d][276]; 64*276=17664 <= 272*72=19584

typedef float    f4v __attribute__((ext_vector_type(4)));
typedef float    f2v __attribute__((ext_vector_type(2)));
typedef _Float16 h2v __attribute__((ext_vector_type(2)));
typedef _Float16 h4v __attribute__((ext_vector_type(4)));

__device__ __forceinline__ float dot2f(float aBits, float bBits, float c) {
#if __has_builtin(__builtin_amdgcn_fdot2)
  return __builtin_amdgcn_fdot2(__builtin_bit_cast(h2v, aBits),
                                __builtin_bit_cast(h2v, bBits), c, false);
#else
  h2v a = __builtin_bit_cast(h2v, aBits);
  h2v b = __builtin_bit_cast(h2v, bBits);
  return c + (float)a.x * (float)b.x + (float)a.y * (float)b.y;
#endif
}

__global__ __launch_bounds__(256, 3)
void cwa_kernel(const float* __restrict__ q, const float* __restrict__ k,
                const float* __restrict__ v, float* __restrict__ out,
                float* __restrict__ attn)
{
  // kvbuf holds K as [u][KV_STRIDE] in P1, then V^T as [d][VT_STRIDE] in P3.
  __shared__ __align__(16) _Float16 kvbuf[UEXT * KV_STRIDE];
  __shared__ __align__(16) _Float16 kq[TQ][DHEAD];
  __shared__ __align__(16) _Float16 sc[TQ][SC_STRIDE];
  __shared__ float rsum[4][TQ];
  __shared__ float rinv[TQ];

  const int t    = threadIdx.x;
  const int lane = t & 63;
  const int wv   = t >> 6;       // wave 0..3
  const int trow = lane >> 4;    // 0..3
  const int tcol = lane & 15;    // 0..15

  const int blk   = blockIdx.x;
  const int bh    = blk >> 7;          // / 128 tiles
  const int i0    = (blk & 127) * TQ;  // first query row of tile
  const int jbase = i0 - 256;          // global key row of staged column u=0

  const size_t base = (size_t)bh * (S_LEN * DHEAD);
  const float* qb = q + base;
  const float* kb = k + base;
  const float* vb = v + base;
  float* abase = attn + (size_t)(bh * S_LEN + i0) * S_LEN;

  const f4v fzero = {0.f, 0.f, 0.f, 0.f};

  // ---------------- P0: stage Q tile + K window as f16 ----------------
  {
    const int r = t >> 4, d4 = t & 15;
    f4v f = *(const f4v*)(qb + (size_t)(i0 + r) * DHEAD + 4 * d4);
    h4v h = { (_Float16)f.x, (_Float16)f.y, (_Float16)f.z, (_Float16)f.w };
    *(h4v*)&kq[r][4 * d4] = h;
  }
  #pragma unroll 4
  for (int w = 0; w < 17; ++w) {
    const int idx = t + 256 * w;       // 0..4351
    const int u = idx >> 4, d4 = idx & 15;
    const int j = jbase + u;
    f4v f = fzero;                      // zero-fill OOB rows
    if (j >= 0 && j < S_LEN) f = *(const f4v*)(kb + (size_t)j * DHEAD + 4 * d4);
    h4v h = { (_Float16)f.x, (_Float16)f.y, (_Float16)f.z, (_Float16)f.w };
    *(h4v*)&kvbuf[u * KV_STRIDE + 4 * d4] = h;
  }
  __syncthreads();

  // ---------------- P1: QK^T (f16 dot2), mask, exp, row sums ----------------
  {
    float acc[4][5];
    #pragma unroll
    for (int i = 0; i < 4; ++i)
      #pragma unroll
      for (int j = 0; j < 5; ++j) acc[i][j] = 0.f;

    const int cbase = 68 * wv + tcol;  // wave owns columns [68*wv, 68*wv+68)

    for (int ds2 = 0; ds2 < 8; ++ds2) {
      f4v qr[4], kr[5];
      #pragma unroll
      for (int i = 0; i < 4; ++i)
        qr[i] = *(const f4v*)&kq[trow + 4 * i][8 * ds2];
      #pragma unroll
      for (int j = 0; j < 4; ++j)
        kr[j] = *(const f4v*)&kvbuf[(cbase + 16 * j) * KV_STRIDE + 8 * ds2];
      kr[4] = (tcol < 4) ? *(const f4v*)&kvbuf[(cbase + 64) * KV_STRIDE + 8 * ds2]
                         : fzero;

      #pragma unroll
      for (int i = 0; i < 4; ++i) {
        #pragma unroll
        for (int j = 0; j < 5; ++j) {
          float a = acc[i][j];
          a = dot2f(qr[i].x, kr[j].x, a);
          a = dot2f(qr[i].y, kr[j].y, a);
          a = dot2f(qr[i].z, kr[j].z, a);
          a = dot2f(qr[i].w, kr[j].w, a);
          acc[i][j] = a;
        }
      }
    }

    float rs[4] = {0.f, 0.f, 0.f, 0.f};
    #pragma unroll
    for (int i = 0; i < 4; ++i) {
      const int r = trow + 4 * i;
      #pragma unroll
      for (int j = 0; j < 5; ++j) {
        if (j == 4 && tcol >= 4) continue;   // only tcol<4 own a 5th column
        const int u = cbase + 16 * j;
        // window: u in [r+1, r+256]; j_global >= 0 <=> u >= 256 - i0
        const bool valid = (u >= r + 1) && (u <= r + 256) && (u >= 256 - i0);
        const float p = valid ? __expf(acc[i][j] * 0.125f) : 0.f;
        sc[r][u] = (_Float16)p;
        rs[i] += p;
      }
    }
    #pragma unroll
    for (int off = 8; off > 0; off >>= 1) {
      #pragma unroll
      for (int i = 0; i < 4; ++i) rs[i] += __shfl_down(rs[i], off, 64);
    }
    if (tcol == 0) {
      #pragma unroll
      for (int i = 0; i < 4; ++i) rsum[wv][trow + 4 * i] = rs[i];
    }
  }
  __syncthreads();

  // ---------------- P2: stage V TRANSPOSED (vt[d][u]) + 1/rowsum ----------------
  #pragma unroll 4
  for (int w = 0; w < 17; ++w) {
    const int idx = t + 256 * w;
    const int u = idx >> 4, d4 = idx & 15;
    const int j = jbase + u;
    f4v f = fzero;
    if (j >= 0 && j < S_LEN) f = *(const f4v*)(vb + (size_t)j * DHEAD + 4 * d4);
    kvbuf[(4 * d4 + 0) * VT_STRIDE + u] = (_Float16)f.x;
    kvbuf[(4 * d4 + 1) * VT_STRIDE + u] = (_Float16)f.y;
    kvbuf[(4 * d4 + 2) * VT_STRIDE + u] = (_Float16)f.z;
    kvbuf[(4 * d4 + 3) * VT_STRIDE + u] = (_Float16)f.w;
  }
  if (t < TQ) {
    rinv[t] = 1.f / (rsum[0][t] + rsum[1][t] + rsum[2][t] + rsum[3][t]);
  }
  __syncthreads();

  // ---------------- P4 (early): band attn writes -> drain under PV compute ----
  for (int idx = t; idx < TQ * 68; idx += 256) {
    const int r  = idx / 68;
    const int u4 = idx - 68 * r;
    const int j  = jbase + 4 * u4;
    if (j < 0) continue;                 // j<0 columns don't exist
    h4v ph = *(const h4v*)&sc[r][4 * u4];
    const float inv = rinv[r];
    f4v val = { (float)ph.x * inv, (float)ph.y * inv,
                (float)ph.z * inv, (float)ph.w * inv };
    *(f4v*)(abase + (size_t)r * S_LEN + j) = val;
  }

  // ---------------- P3: PV via fdot2 on V^T (no conversions) + out store ------
  {
    const int tr = t >> 4;   // query row 0..15
    const int td = t & 15;   // d strip; lane owns d = td + {0,16,32,48}
    const _Float16* vt0 = kvbuf + (size_t)(td +  0) * VT_STRIDE;
    const _Float16* vt1 = kvbuf + (size_t)(td + 16) * VT_STRIDE;
    const _Float16* vt2 = kvbuf + (size_t)(td + 32) * VT_STRIDE;
    const _Float16* vt3 = kvbuf + (size_t)(td + 48) * VT_STRIDE;
    f4v acc = fzero;

    #pragma unroll 4
    for (int u = 0; u < UEXT; u += 4) {
      f2v ph = *(const f2v*)&sc[tr][u];
      f2v a0 = *(const f2v*)(vt0 + u);
      f2v a1 = *(const f2v*)(vt1 + u);
      f2v a2 = *(const f2v*)(vt2 + u);
      f2v a3 = *(const f2v*)(vt3 + u);
      acc.x = dot2f(ph.x, a0.x, acc.x); acc.x = dot2f(ph.y, a0.y, acc.x);
      acc.y = dot2f(ph.x, a1.x, acc.y); acc.y = dot2f(ph.y, a1.y, acc.y);
      acc.z = dot2f(ph.x, a2.x, acc.z); acc.z = dot2f(ph.y, a2.y, acc.z);
      acc.w = dot2f(ph.x, a3.x, acc.w); acc.w = dot2f(ph.y, a3.y, acc.w);
    }
    const float inv = rinv[tr];
    float* op = out + (size_t)(bh * S_LEN + i0 + tr) * DHEAD + td;
    op[ 0] = acc.x * inv;
    op[16] = acc.y * inv;
    op[32] = acc.z * inv;
    op[48] = acc.w * inv;
  }
}

extern "C" void kernel_launch(void* const* d_in, const int* in_sizes, int n_in,
                              void* d_out, int out_size, void* d_ws, size_t ws_size,
                              hipStream_t stream) {
  const float* q = (const float*)d_in[0];
  const float* k = (const float*)d_in[1];
  const float* v = (const float*)d_in[2];
  float* out  = (float*)d_out;
  float* attn = out + (size_t)2 * 16 * 2048 * 64;   // out first, then attn

  // Zero the full attn tensor via memset engine (full-line writes, no RMW);
  // the kernel then overwrites only the in-window band.
  hipMemsetAsync(attn, 0, (size_t)2 * 16 * 2048 * 2048 * sizeof(float), stream);

  dim3 grid(4096), block(256);                      // 32 bh * 128 tiles
  hipLaunchKernelGGL(cwa_kernel, grid, block, 0, stream, q, k, v, out, attn);
}